// Round 14
// baseline (62.310 us; speedup 1.0000x reference)
//
#include <hip/hip_runtime.h>
#include <math.h>

#define NB 4      // batch
#define TD 128    // T_DEC
#define SE 1024   // S_ENC
#define DD 512    // D
#define UN 128    // UNITS
#define NROWS 4608          // 4096 enc + 512 dec
#define KSPLIT 4
#define SSPLIT 8            // ctx s-chunks

// raw v_exp_f32: D = 2^S0 (operands pre-scaled by 2*log2e at redT time)
__device__ __forceinline__ float exp2_raw(float x) {
  float r;
  asm("v_exp_f32 %0, %1" : "=v"(r) : "v"(x));
  return r;
}

// ---------------------------------------------------------------------------
// K1a: projection partials. grid (72, 4): blockIdx.x = row-block (64 rows),
// blockIdx.y = ks (K slice of 128). blk 0..63 -> enc rows, 64..71 -> dec.
// Stage 64 rows x 128 k (32 KB) in LDS; thread = (u2, 16 rows in 2 halves):
// 32 FMA per coalesced float2 W load (W regs reused across halves).
// W traffic = 1152 waves x 64 KB = 74 MB L2 (half of round-13).
__global__ __launch_bounds__(256, 4) void k_proj_part(const float* __restrict__ enc,
                                                      const float* __restrict__ dec,
                                                      const float* __restrict__ W1,
                                                      const float* __restrict__ W2,
                                                      float* __restrict__ part) {
  __shared__ __align__(16) float At[64 * 128];   // 32 KB

  const int tx = threadIdx.x;
  const int rb = blockIdx.x;            // 0..71
  const int ks = blockIdx.y;            // 0..3
  const bool is_enc = rb < 64;
  const int row_base = rb * 64;         // global row numbering 0..4607
  const float* __restrict__ src = is_enc
      ? (enc + (size_t)row_base * DD)
      : (dec + (size_t)(row_base - NB * SE) * DD);
  const float* __restrict__ W = is_enc ? W1 : W2;
  const int kb = ks * 128;

  // stage: 64 rows x 128 k = 2048 float4, 8 per thread, 128B coalesced runs
#pragma unroll
  for (int i = 0; i < 8; ++i) {
    const int idx = i * 256 + tx;       // 0..2047
    const int row = idx >> 5;           // 32 float4 per row
    const int c4 = (idx & 31) * 4;
    *(float4*)&At[row * 128 + c4] = *(const float4*)(src + (size_t)row * DD + kb + c4);
  }
  __syncthreads();

  const int u2 = (tx & 63) * 2;
  const int r0 = (tx >> 6) * 16;        // wave-uniform row group (16 rows)
  const float* __restrict__ Wp = W + (size_t)kb * UN + u2;

  float acc[16][2] = {};
  for (int k = 0; k < 128; k += 4) {
    float2 wv[4];
#pragma unroll
    for (int j = 0; j < 4; ++j)
      wv[j] = *(const float2*)(Wp + (size_t)(k + j) * UN);
#pragma unroll
    for (int half = 0; half < 2; ++half) {
      float4 a[8];
#pragma unroll
      for (int r = 0; r < 8; ++r)
        a[r] = *(const float4*)&At[(r0 + half * 8 + r) * 128 + k];  // broadcast
#pragma unroll
      for (int j = 0; j < 4; ++j) {
#pragma unroll
        for (int r = 0; r < 8; ++r) {
          const float arj = ((const float*)&a[r])[j];
          acc[half * 8 + r][0] = fmaf(arj, wv[j].x, acc[half * 8 + r][0]);
          acc[half * 8 + r][1] = fmaf(arj, wv[j].y, acc[half * 8 + r][1]);
        }
      }
    }
  }

  float* pb = part + ((size_t)ks * NROWS + row_base + r0) * UN + u2;
#pragma unroll
  for (int r = 0; r < 16; ++r)
    *(float2*)(pb + (size_t)r * UN) = make_float2(acc[r][0], acc[r][1]);
}

// ---------------------------------------------------------------------------
// K1b: reduce 4 K-partials + bias, then PRE-SCALE by 2*log2e (consumed only
// by k_score's exp2-based tanh). enc rows -> wencT (transposed via LDS),
// dec rows -> wdec.
__global__ __launch_bounds__(256, 4) void k_redT(const float* __restrict__ part,
                                                 const float* __restrict__ b1,
                                                 const float* __restrict__ b2,
                                                 float* __restrict__ wencT,
                                                 float* __restrict__ wdec) {
  __shared__ __align__(16) float Tt[16][132];
  const int tx = threadIdx.x;
  const int rb = blockIdx.x;
  const int row_base = rb * 16;
  const bool is_enc = rb < 256;
  const int r = tx >> 4;                // 0..15
  const int u0 = (tx & 15) * 8;         // 8 u per thread
  const size_t N = (size_t)NROWS * UN;
  const float K2 = 2.88539008f;         // 2*log2(e)

  const float* p = part + (size_t)(row_base + r) * UN + u0;
  float4 sa = *(const float4*)(p);
  float4 sb = *(const float4*)(p + 4);
#pragma unroll
  for (int s = 1; s < KSPLIT; ++s) {
    const float4 qa = *(const float4*)(p + (size_t)s * N);
    const float4 qb = *(const float4*)(p + (size_t)s * N + 4);
    sa.x += qa.x; sa.y += qa.y; sa.z += qa.z; sa.w += qa.w;
    sb.x += qb.x; sb.y += qb.y; sb.z += qb.z; sb.w += qb.w;
  }
  const float* bias = is_enc ? b1 : b2;
  const float4 ba = *(const float4*)(bias + u0);
  const float4 bb = *(const float4*)(bias + u0 + 4);
  sa.x = K2 * (sa.x + ba.x); sa.y = K2 * (sa.y + ba.y);
  sa.z = K2 * (sa.z + ba.z); sa.w = K2 * (sa.w + ba.w);
  sb.x = K2 * (sb.x + bb.x); sb.y = K2 * (sb.y + bb.y);
  sb.z = K2 * (sb.z + bb.z); sb.w = K2 * (sb.w + bb.w);

  if (is_enc) {
    *(float4*)&Tt[r][u0] = sa;
    *(float4*)&Tt[r][u0 + 4] = sb;
    __syncthreads();
    const int b = row_base >> 10;
    const int s0 = row_base & 1023;
    const int u = tx >> 1;
    const int sh = tx & 1;
    float o[8];
#pragma unroll
    for (int j = 0; j < 8; ++j) o[j] = Tt[sh * 8 + j][u];
    float* dst = wencT + (size_t)(b * UN + u) * SE + s0 + sh * 8;
    *(float4*)dst = make_float4(o[0], o[1], o[2], o[3]);
    *(float4*)(dst + 4) = make_float4(o[4], o[5], o[6], o[7]);
  } else {
    float* dst = wdec + (size_t)(row_base - NB * SE + r) * UN + u0;
    *(float4*)dst = sa;
    *(float4*)(dst + 4) = sb;
  }
}

// ---------------------------------------------------------------------------
// K2: scores + softmax. One WG (1024 thr, 16 waves) per (b, t-pair): grid 256.
// exp-sharing: exp2(w+d_t) = exp2(w)*E_t with E_t = exp2(wdl_t) precomputed
// in LDS. Per (s,u): 1 exp + 2 rcp + 4 fma (was 2 exp + 2 rcp + 6 VALU).
// score' = sum_u (-2 v_u) * rcp(fma(e, E_t, 1)); consts dropped (softmax
// shift-invariant, incl. v_b).
__global__ __launch_bounds__(1024, 1) void k_score(const float* __restrict__ wdec,
                                                   const float* __restrict__ v,
                                                   const float* __restrict__ wencT,
                                                   float* __restrict__ attn) {
  __shared__ __align__(16) float wdE[2][UN];        // exp2 of pre-scaled wdec
  __shared__ __align__(16) float nv2[UN];
  __shared__ __align__(16) float parts[4][2][SE];   // 32 KB
  __shared__ float redM[2][4], redS[2][4];

  const int wg = blockIdx.x;          // 0..255
  const int b = wg >> 6;
  const int t0 = (wg & 63) * 2;
  const int bt0 = b * TD + t0;
  const int tx = threadIdx.x;         // 0..1023

  if (tx < 2 * UN) {
    const int tt = tx >> 7, u = tx & 127;
    wdE[tt][u] = exp2_raw(wdec[(size_t)(bt0 + tt) * UN + u]);   // E_t[u]
    if (tx < UN) nv2[tx] = -2.0f * v[tx];
  }
  __syncthreads();

  const int sq = tx & 255;            // s-quad 0..255
  const int uq = tx >> 8;             // u quarter 0..3
  const float* wp = wencT + (size_t)(b * UN + uq * 32) * SE + sq * 4;

  float a0[4] = {}, a1[4] = {};
#pragma unroll 4
  for (int ui = 0; ui < 32; ++ui) {
    const int u = uq * 32 + ui;
    const float4 w = *(const float4*)(wp + (size_t)ui * SE);
    const float nvu = nv2[u];
    const float E0 = wdE[0][u];
    const float E1 = wdE[1][u];
#pragma unroll
    for (int j = 0; j < 4; ++j) {
      const float e = exp2_raw(((const float*)&w)[j]);   // shared by both t
      const float r0 = __builtin_amdgcn_rcpf(fmaf(e, E0, 1.0f));
      a0[j] = fmaf(nvu, r0, a0[j]);
      const float r1 = __builtin_amdgcn_rcpf(fmaf(e, E1, 1.0f));
      a1[j] = fmaf(nvu, r1, a1[j]);
    }
  }
  *(float4*)&parts[uq][0][sq * 4] = make_float4(a0[0], a0[1], a0[2], a0[3]);
  *(float4*)&parts[uq][1][sq * 4] = make_float4(a1[0], a1[1], a1[2], a1[3]);
  __syncthreads();

  // threads 0..511: tt = tx>>8, q = tx&255 -> 4 s-values each
  float sc[4], pv[4];
  const int tt = tx >> 8;             // valid for tx<512
  const int q = tx & 255;
  if (tx < 512) {
    const float4 g0 = *(const float4*)&parts[0][tt][q * 4];
    const float4 g1 = *(const float4*)&parts[1][tt][q * 4];
    const float4 g2 = *(const float4*)&parts[2][tt][q * 4];
    const float4 g3 = *(const float4*)&parts[3][tt][q * 4];
    sc[0] = (g0.x + g1.x) + (g2.x + g3.x);
    sc[1] = (g0.y + g1.y) + (g2.y + g3.y);
    sc[2] = (g0.z + g1.z) + (g2.z + g3.z);
    sc[3] = (g0.w + g1.w) + (g2.w + g3.w);
    float m = fmaxf(fmaxf(sc[0], sc[1]), fmaxf(sc[2], sc[3]));
#pragma unroll
    for (int off = 32; off; off >>= 1) m = fmaxf(m, __shfl_xor(m, off));
    if ((tx & 63) == 0) redM[tt][(tx >> 6) & 3] = m;
  }
  __syncthreads();
  if (tx < 512) {
    const float m = fmaxf(fmaxf(redM[tt][0], redM[tt][1]),
                          fmaxf(redM[tt][2], redM[tt][3]));
    float s = 0.f;
#pragma unroll
    for (int j = 0; j < 4; ++j) { pv[j] = __expf(sc[j] - m); s += pv[j]; }
#pragma unroll
    for (int off = 32; off; off >>= 1) s += __shfl_xor(s, off);
    if ((tx & 63) == 0) redS[tt][(tx >> 6) & 3] = s;
  }
  __syncthreads();
  if (tx < 512) {
    const float s = (redS[tt][0] + redS[tt][1]) + (redS[tt][2] + redS[tt][3]);
    const float rinv = 1.0f / s;
    float* arow = attn + (size_t)(bt0 + tt) * SE + q * 4;
    *(float4*)arow = make_float4(pv[0] * rinv, pv[1] * rinv, pv[2] * rinv, pv[3] * rinv);
  }
}

// ---------------------------------------------------------------------------
// K3: partial context over s-chunks of 128. grid = sc(8) x tg(16) x b(4) = 512.
// WG: 8 t-rows x all 512 d; thread = (d quad = (tx&127)*4, t-half = tx>>7 ->
// 4 rows). Per s: 1 float4 enc load + 4 wave-uniform LDS reads + 16 FMA.
__global__ __launch_bounds__(256, 2) void k_ctx_part(const float* __restrict__ attn,
                                                     const float* __restrict__ enc,
                                                     float* __restrict__ part) {
  __shared__ __align__(16) float at[8][128];
  const int wg = blockIdx.x;
  const int sch = wg & 7;
  const int tg = (wg >> 3) & 15;
  const int b = wg >> 7;
  const int tx = threadIdx.x;
  const int sbeg = sch * 128;
  {
    const int i = tx >> 5, c = (tx & 31) * 4;   // 8 rows x 32 float4
    *(float4*)&at[i][c] =
        *(const float4*)(attn + (size_t)(b * TD + tg * 8 + i) * SE + sbeg + c);
  }
  __syncthreads();
  const int d0 = (tx & 127) * 4;
  const int th = tx >> 7;               // 0/1: rows th*4 .. th*4+3 (wave-uniform)
  const float* ep = enc + ((size_t)b * SE + sbeg) * DD + d0;
  float4 acc[4] = {};
  for (int s = 0; s < 128; ++s) {
    const float4 ev = *(const float4*)(ep + (size_t)s * DD);
#pragma unroll
    for (int i = 0; i < 4; ++i) {
      const float aij = at[th * 4 + i][s];
      acc[i].x = fmaf(aij, ev.x, acc[i].x);
      acc[i].y = fmaf(aij, ev.y, acc[i].y);
      acc[i].z = fmaf(aij, ev.z, acc[i].z);
      acc[i].w = fmaf(aij, ev.w, acc[i].w);
    }
  }
  float* pb = part + ((size_t)sch * (NB * TD) + b * TD + tg * 8 + th * 4) * DD + d0;
#pragma unroll
  for (int i = 0; i < 4; ++i)
    *(float4*)(pb + (size_t)i * DD) = acc[i];
}

// ---------------------------------------------------------------------------
// K4: ctx = sum of 8 partials. grid 256 x 256 thr, float4/thread.
__global__ __launch_bounds__(256, 2) void k_red(const float* __restrict__ part,
                                                float* __restrict__ ctx) {
  const size_t N = (size_t)NB * TD * DD;
  const size_t i = ((size_t)blockIdx.x * 256 + threadIdx.x) * 4;
  float4 o = *(const float4*)(part + i);
#pragma unroll
  for (int s = 1; s < SSPLIT; ++s) {
    const float4 q = *(const float4*)(part + (size_t)s * N + i);
    o.x += q.x; o.y += q.y; o.z += q.z; o.w += q.w;
  }
  *(float4*)(ctx + i) = o;
}

extern "C" void kernel_launch(void* const* d_in, const int* in_sizes, int n_in,
                              void* d_out, int out_size, void* d_ws, size_t ws_size,
                              hipStream_t stream) {
  const float* dec = (const float*)d_in[0];
  const float* enc = (const float*)d_in[1];
  const float* W1  = (const float*)d_in[2];
  const float* b1  = (const float*)d_in[3];
  const float* W2  = (const float*)d_in[4];
  const float* b2  = (const float*)d_in[5];
  const float* v   = (const float*)d_in[6];
  // d_in[7] = v_b: skipped — softmax is invariant to a uniform score shift.

  float* ctx  = (float*)d_out;                        // [4,128,512]
  float* attn = (float*)d_out + (size_t)NB * TD * DD; // [4,128,1024]

  float* ws    = (float*)d_ws;
  float* wencT = ws;                                  // [4][128][1024] 2 MB
  float* wdec  = wencT + (size_t)NB * UN * SE;        // [512][128] 256 KB
  // scratch shared in time: proj partials (9 MB) then ctx partials (8 MB)
  float* scratch = wdec + (size_t)NB * TD * UN;
  float* projpart = scratch;                          // [4][4608][128]
  float* ctxpart  = scratch;                          // [8][512][512]

  hipLaunchKernelGGL(k_proj_part, dim3(72, KSPLIT), dim3(256), 0, stream,
                     enc, dec, W1, W2, projpart);
  hipLaunchKernelGGL(k_redT, dim3(288), dim3(256), 0, stream,
                     projpart, b1, b2, wencT, wdec);
  hipLaunchKernelGGL(k_score, dim3(256), dim3(1024), 0, stream,
                     wdec, v, wencT, attn);
  hipLaunchKernelGGL(k_ctx_part, dim3(512), dim3(256), 0, stream, attn, enc, ctxpart);
  hipLaunchKernelGGL(k_red, dim3(256), dim3(256), 0, stream, ctxpart, ctx);
}

// Round 15
// 57.243 us; speedup vs baseline: 1.0885x; 1.0885x over previous
//
#include <hip/hip_runtime.h>
#include <math.h>

#define NB 4      // batch
#define TD 128    // T_DEC
#define SE 1024   // S_ENC
#define DD 512    // D
#define UN 128    // UNITS
#define NROWS 4608          // 4096 enc + 512 dec
#define KSPLIT 4
#define SSPLIT 8            // ctx s-chunks

// raw v_exp_f32: D = 2^S0 (operands pre-scaled by 2*log2e at redT time)
__device__ __forceinline__ float exp2_raw(float x) {
  float r;
  asm("v_exp_f32 %0, %1" : "=v"(r) : "v"(x));
  return r;
}

// ---------------------------------------------------------------------------
// K1a: projection partials. grid (144, 4): blockIdx.x = row-block (32 rows),
// blockIdx.y = ks (K slice of 128). blk 0..127 -> enc rows, 128..143 -> dec.
// Stage 32 rows x 128 k (16 KB) in LDS; thread = (u2, 8 rows): 16 FMA per
// coalesced float2 W load, 8 indep chains. 576 WGs = 9 waves/CU (validated
// R10/R13 config; 64-row variant at 4.5 waves/CU regressed in R14).
__global__ __launch_bounds__(256, 4) void k_proj_part(const float* __restrict__ enc,
                                                      const float* __restrict__ dec,
                                                      const float* __restrict__ W1,
                                                      const float* __restrict__ W2,
                                                      float* __restrict__ part) {
  __shared__ __align__(16) float At[32 * 128];   // 16 KB

  const int tx = threadIdx.x;
  const int rb = blockIdx.x;            // 0..143
  const int ks = blockIdx.y;            // 0..3
  const bool is_enc = rb < 128;
  const int row_base = rb * 32;         // global row numbering 0..4607
  const float* __restrict__ src = is_enc
      ? (enc + (size_t)row_base * DD)
      : (dec + (size_t)(row_base - NB * SE) * DD);
  const float* __restrict__ W = is_enc ? W1 : W2;
  const int kb = ks * 128;

#pragma unroll
  for (int i = 0; i < 4; ++i) {
    const int idx = i * 256 + tx;       // 0..1023
    const int row = idx >> 5;           // 32 float4 per row
    const int c4 = (idx & 31) * 4;
    *(float4*)&At[row * 128 + c4] = *(const float4*)(src + (size_t)row * DD + kb + c4);
  }
  __syncthreads();

  const int u2 = (tx & 63) * 2;
  const int r0 = (tx >> 6) * 8;         // wave-uniform row group (8 rows)
  const float* __restrict__ Wp = W + (size_t)kb * UN + u2;

  float acc[8][2] = {};
  for (int k = 0; k < 128; k += 4) {
    float4 a[8];
#pragma unroll
    for (int r = 0; r < 8; ++r)
      a[r] = *(const float4*)&At[(r0 + r) * 128 + k];   // wave-uniform broadcast
#pragma unroll
    for (int j = 0; j < 4; ++j) {
      const float2 w = *(const float2*)(Wp + (size_t)(k + j) * UN);
#pragma unroll
      for (int r = 0; r < 8; ++r) {
        const float arj = ((const float*)&a[r])[j];
        acc[r][0] = fmaf(arj, w.x, acc[r][0]);
        acc[r][1] = fmaf(arj, w.y, acc[r][1]);
      }
    }
  }

  float* pb = part + ((size_t)ks * NROWS + row_base + r0) * UN + u2;
#pragma unroll
  for (int r = 0; r < 8; ++r)
    *(float2*)(pb + (size_t)r * UN) = make_float2(acc[r][0], acc[r][1]);
}

// ---------------------------------------------------------------------------
// K1b: reduce 4 K-partials + bias, then PRE-SCALE by 2*log2e (consumed only
// by k_score's exp2-based tanh). enc rows -> wencT (transposed via LDS),
// dec rows -> wdec.
__global__ __launch_bounds__(256, 4) void k_redT(const float* __restrict__ part,
                                                 const float* __restrict__ b1,
                                                 const float* __restrict__ b2,
                                                 float* __restrict__ wencT,
                                                 float* __restrict__ wdec) {
  __shared__ __align__(16) float Tt[16][132];
  const int tx = threadIdx.x;
  const int rb = blockIdx.x;
  const int row_base = rb * 16;
  const bool is_enc = rb < 256;
  const int r = tx >> 4;                // 0..15
  const int u0 = (tx & 15) * 8;         // 8 u per thread
  const size_t N = (size_t)NROWS * UN;
  const float K2 = 2.88539008f;         // 2*log2(e)

  const float* p = part + (size_t)(row_base + r) * UN + u0;
  float4 sa = *(const float4*)(p);
  float4 sb = *(const float4*)(p + 4);
#pragma unroll
  for (int s = 1; s < KSPLIT; ++s) {
    const float4 qa = *(const float4*)(p + (size_t)s * N);
    const float4 qb = *(const float4*)(p + (size_t)s * N + 4);
    sa.x += qa.x; sa.y += qa.y; sa.z += qa.z; sa.w += qa.w;
    sb.x += qb.x; sb.y += qb.y; sb.z += qb.z; sb.w += qb.w;
  }
  const float* bias = is_enc ? b1 : b2;
  const float4 ba = *(const float4*)(bias + u0);
  const float4 bb = *(const float4*)(bias + u0 + 4);
  sa.x = K2 * (sa.x + ba.x); sa.y = K2 * (sa.y + ba.y);
  sa.z = K2 * (sa.z + ba.z); sa.w = K2 * (sa.w + ba.w);
  sb.x = K2 * (sb.x + bb.x); sb.y = K2 * (sb.y + bb.y);
  sb.z = K2 * (sb.z + bb.z); sb.w = K2 * (sb.w + bb.w);

  if (is_enc) {
    *(float4*)&Tt[r][u0] = sa;
    *(float4*)&Tt[r][u0 + 4] = sb;
    __syncthreads();
    const int b = row_base >> 10;
    const int s0 = row_base & 1023;
    const int u = tx >> 1;
    const int sh = tx & 1;
    float o[8];
#pragma unroll
    for (int j = 0; j < 8; ++j) o[j] = Tt[sh * 8 + j][u];
    float* dst = wencT + (size_t)(b * UN + u) * SE + s0 + sh * 8;
    *(float4*)dst = make_float4(o[0], o[1], o[2], o[3]);
    *(float4*)(dst + 4) = make_float4(o[4], o[5], o[6], o[7]);
  } else {
    float* dst = wdec + (size_t)(row_base - NB * SE + r) * UN + u0;
    *(float4*)dst = sa;
    *(float4*)(dst + 4) = sb;
  }
}

// ---------------------------------------------------------------------------
// K2: scores + softmax. One WG (1024 thr, 16 waves) per (b, t-pair): grid 256.
// exp-sharing: exp2(w+d_t) = exp2(w)*E_t with E_t = exp2(wdl_t) precomputed
// in LDS. Per (s,u): 1 exp + 2 rcp + 4 fma.
// score' = sum_u (-2 v_u) * rcp(fma(e, E_t, 1)); consts dropped (softmax
// shift-invariant, incl. v_b).
__global__ __launch_bounds__(1024, 1) void k_score(const float* __restrict__ wdec,
                                                   const float* __restrict__ v,
                                                   const float* __restrict__ wencT,
                                                   float* __restrict__ attn) {
  __shared__ __align__(16) float wdE[2][UN];        // exp2 of pre-scaled wdec
  __shared__ __align__(16) float nv2[UN];
  __shared__ __align__(16) float parts[4][2][SE];   // 32 KB
  __shared__ float redM[2][4], redS[2][4];

  const int wg = blockIdx.x;          // 0..255
  const int b = wg >> 6;
  const int t0 = (wg & 63) * 2;
  const int bt0 = b * TD + t0;
  const int tx = threadIdx.x;         // 0..1023

  if (tx < 2 * UN) {
    const int tt = tx >> 7, u = tx & 127;
    wdE[tt][u] = exp2_raw(wdec[(size_t)(bt0 + tt) * UN + u]);   // E_t[u]
    if (tx < UN) nv2[tx] = -2.0f * v[tx];
  }
  __syncthreads();

  const int sq = tx & 255;            // s-quad 0..255
  const int uq = tx >> 8;             // u quarter 0..3
  const float* wp = wencT + (size_t)(b * UN + uq * 32) * SE + sq * 4;

  float a0[4] = {}, a1[4] = {};
#pragma unroll 4
  for (int ui = 0; ui < 32; ++ui) {
    const int u = uq * 32 + ui;
    const float4 w = *(const float4*)(wp + (size_t)ui * SE);
    const float nvu = nv2[u];
    const float E0 = wdE[0][u];
    const float E1 = wdE[1][u];
#pragma unroll
    for (int j = 0; j < 4; ++j) {
      const float e = exp2_raw(((const float*)&w)[j]);   // shared by both t
      const float r0 = __builtin_amdgcn_rcpf(fmaf(e, E0, 1.0f));
      a0[j] = fmaf(nvu, r0, a0[j]);
      const float r1 = __builtin_amdgcn_rcpf(fmaf(e, E1, 1.0f));
      a1[j] = fmaf(nvu, r1, a1[j]);
    }
  }
  *(float4*)&parts[uq][0][sq * 4] = make_float4(a0[0], a0[1], a0[2], a0[3]);
  *(float4*)&parts[uq][1][sq * 4] = make_float4(a1[0], a1[1], a1[2], a1[3]);
  __syncthreads();

  // threads 0..511: tt = tx>>8, q = tx&255 -> 4 s-values each
  float sc[4], pv[4];
  const int tt = tx >> 8;             // valid for tx<512
  const int q = tx & 255;
  if (tx < 512) {
    const float4 g0 = *(const float4*)&parts[0][tt][q * 4];
    const float4 g1 = *(const float4*)&parts[1][tt][q * 4];
    const float4 g2 = *(const float4*)&parts[2][tt][q * 4];
    const float4 g3 = *(const float4*)&parts[3][tt][q * 4];
    sc[0] = (g0.x + g1.x) + (g2.x + g3.x);
    sc[1] = (g0.y + g1.y) + (g2.y + g3.y);
    sc[2] = (g0.z + g1.z) + (g2.z + g3.z);
    sc[3] = (g0.w + g1.w) + (g2.w + g3.w);
    float m = fmaxf(fmaxf(sc[0], sc[1]), fmaxf(sc[2], sc[3]));
#pragma unroll
    for (int off = 32; off; off >>= 1) m = fmaxf(m, __shfl_xor(m, off));
    if ((tx & 63) == 0) redM[tt][(tx >> 6) & 3] = m;
  }
  __syncthreads();
  if (tx < 512) {
    const float m = fmaxf(fmaxf(redM[tt][0], redM[tt][1]),
                          fmaxf(redM[tt][2], redM[tt][3]));
    float s = 0.f;
#pragma unroll
    for (int j = 0; j < 4; ++j) { pv[j] = __expf(sc[j] - m); s += pv[j]; }
#pragma unroll
    for (int off = 32; off; off >>= 1) s += __shfl_xor(s, off);
    if ((tx & 63) == 0) redS[tt][(tx >> 6) & 3] = s;
  }
  __syncthreads();
  if (tx < 512) {
    const float s = (redS[tt][0] + redS[tt][1]) + (redS[tt][2] + redS[tt][3]);
    const float rinv = 1.0f / s;
    float* arow = attn + (size_t)(bt0 + tt) * SE + q * 4;
    *(float4*)arow = make_float4(pv[0] * rinv, pv[1] * rinv, pv[2] * rinv, pv[3] * rinv);
  }
}

// ---------------------------------------------------------------------------
// K3: partial context over s-chunks of 128. grid = sc(8) x tg(16) x b(4) = 512.
// WG: 8 t-rows x all 512 d; thread = (d quad = (tx&127)*4, t-half = tx>>7 ->
// 4 rows). Per s: 1 float4 enc load + 4 wave-uniform LDS reads + 16 FMA.
__global__ __launch_bounds__(256, 2) void k_ctx_part(const float* __restrict__ attn,
                                                     const float* __restrict__ enc,
                                                     float* __restrict__ part) {
  __shared__ __align__(16) float at[8][128];
  const int wg = blockIdx.x;
  const int sch = wg & 7;
  const int tg = (wg >> 3) & 15;
  const int b = wg >> 7;
  const int tx = threadIdx.x;
  const int sbeg = sch * 128;
  {
    const int i = tx >> 5, c = (tx & 31) * 4;   // 8 rows x 32 float4
    *(float4*)&at[i][c] =
        *(const float4*)(attn + (size_t)(b * TD + tg * 8 + i) * SE + sbeg + c);
  }
  __syncthreads();
  const int d0 = (tx & 127) * 4;
  const int th = tx >> 7;               // 0/1: rows th*4 .. th*4+3 (wave-uniform)
  const float* ep = enc + ((size_t)b * SE + sbeg) * DD + d0;
  float4 acc[4] = {};
  for (int s = 0; s < 128; ++s) {
    const float4 ev = *(const float4*)(ep + (size_t)s * DD);
#pragma unroll
    for (int i = 0; i < 4; ++i) {
      const float aij = at[th * 4 + i][s];
      acc[i].x = fmaf(aij, ev.x, acc[i].x);
      acc[i].y = fmaf(aij, ev.y, acc[i].y);
      acc[i].z = fmaf(aij, ev.z, acc[i].z);
      acc[i].w = fmaf(aij, ev.w, acc[i].w);
    }
  }
  float* pb = part + ((size_t)sch * (NB * TD) + b * TD + tg * 8 + th * 4) * DD + d0;
#pragma unroll
  for (int i = 0; i < 4; ++i)
    *(float4*)(pb + (size_t)i * DD) = acc[i];
}

// ---------------------------------------------------------------------------
// K4: ctx = sum of 8 partials. grid 256 x 256 thr, float4/thread.
__global__ __launch_bounds__(256, 2) void k_red(const float* __restrict__ part,
                                                float* __restrict__ ctx) {
  const size_t N = (size_t)NB * TD * DD;
  const size_t i = ((size_t)blockIdx.x * 256 + threadIdx.x) * 4;
  float4 o = *(const float4*)(part + i);
#pragma unroll
  for (int s = 1; s < SSPLIT; ++s) {
    const float4 q = *(const float4*)(part + (size_t)s * N + i);
    o.x += q.x; o.y += q.y; o.z += q.z; o.w += q.w;
  }
  *(float4*)(ctx + i) = o;
}

extern "C" void kernel_launch(void* const* d_in, const int* in_sizes, int n_in,
                              void* d_out, int out_size, void* d_ws, size_t ws_size,
                              hipStream_t stream) {
  const float* dec = (const float*)d_in[0];
  const float* enc = (const float*)d_in[1];
  const float* W1  = (const float*)d_in[2];
  const float* b1  = (const float*)d_in[3];
  const float* W2  = (const float*)d_in[4];
  const float* b2  = (const float*)d_in[5];
  const float* v   = (const float*)d_in[6];
  // d_in[7] = v_b: skipped — softmax is invariant to a uniform score shift.

  float* ctx  = (float*)d_out;                        // [4,128,512]
  float* attn = (float*)d_out + (size_t)NB * TD * DD; // [4,128,1024]

  float* ws    = (float*)d_ws;
  float* wencT = ws;                                  // [4][128][1024] 2 MB
  float* wdec  = wencT + (size_t)NB * UN * SE;        // [512][128] 256 KB
  // scratch shared in time: proj partials (9 MB) then ctx partials (8 MB)
  float* scratch = wdec + (size_t)NB * TD * UN;
  float* projpart = scratch;                          // [4][4608][128]
  float* ctxpart  = scratch;                          // [8][512][512]

  hipLaunchKernelGGL(k_proj_part, dim3(144, KSPLIT), dim3(256), 0, stream,
                     enc, dec, W1, W2, projpart);
  hipLaunchKernelGGL(k_redT, dim3(288), dim3(256), 0, stream,
                     projpart, b1, b2, wencT, wdec);
  hipLaunchKernelGGL(k_score, dim3(256), dim3(1024), 0, stream,
                     wdec, v, wencT, attn);
  hipLaunchKernelGGL(k_ctx_part, dim3(512), dim3(256), 0, stream, attn, enc, ctxpart);
  hipLaunchKernelGGL(k_red, dim3(256), dim3(256), 0, stream, ctxpart, ctx);
}

// Round 16
// 52.544 us; speedup vs baseline: 1.1859x; 1.0894x over previous
//
#include <hip/hip_runtime.h>
#include <math.h>

#define NB 4      // batch
#define TD 128    // T_DEC
#define SE 1024   // S_ENC
#define DD 512    // D
#define UN 128    // UNITS
#define KSPLIT 4
#define SSPLIT 8            // ctx s-chunks

// raw v_exp_f32: D = 2^S0 (operands pre-scaled by 2*log2e at proj time)
__device__ __forceinline__ float exp2_raw(float x) {
  float r;
  asm("v_exp_f32 %0, %1" : "=v"(r) : "v"(x));
  return r;
}

// ---------------------------------------------------------------------------
// K1: projections, fused KSPLIT-in-WG (replaces k_proj_part + k_redT).
// grid 288 x 512 thr (8 waves): blk 0..255 -> 16 enc rows, 256..287 -> 16 dec.
// Wave = (ks = wave&3 -> 128-k slice, rh = wave>>2 -> 8-row half).
// Thread: 8 rows x 2 u x 128 k = 16 FMA per coalesced float2 W load (R13's
// validated ratio); 2304 waves = 9 waves/CU (R13's validated residency).
// k-partials reduced via LDS (one extra barrier), bias + 2*log2e pre-scale
// fused, enc written TRANSPOSED to wencT[b][u][s], dec row-major to wdec.
// W read once per WG -> 74 MB L2 total (half of the split version).
__global__ __launch_bounds__(512, 2) void k_proj(const float* __restrict__ enc,
                                                 const float* __restrict__ dec,
                                                 const float* __restrict__ W1,
                                                 const float* __restrict__ b1,
                                                 const float* __restrict__ W2,
                                                 const float* __restrict__ b2,
                                                 float* __restrict__ wencT,
                                                 float* __restrict__ wdec) {
  __shared__ __align__(16) float At[16 * DD];          // 32 KB
  __shared__ float red[KSPLIT][16][129];               // 33 KB (pad vs banks)

  const int tx = threadIdx.x;           // 0..511
  const int rb = blockIdx.x;            // 0..287
  const bool is_enc = rb < 256;
  const int row_base = rb * 16;         // global row numbering
  const float* __restrict__ src = is_enc
      ? (enc + (size_t)row_base * DD)
      : (dec + (size_t)(row_base - NB * SE) * DD);
  const float* __restrict__ W = is_enc ? W1 : W2;
  const float* __restrict__ bias = is_enc ? b1 : b2;
  const float K2 = 2.88539008f;         // 2*log2(e)

  // stage 16 rows = 8192 contiguous floats (2048 float4, 4/thread)
#pragma unroll
  for (int i = 0; i < 4; ++i) {
    const int idx = (i * 512 + tx) * 4;
    *(float4*)&At[idx] = *(const float4*)(src + idx);
  }
  __syncthreads();

  const int u2 = (tx & 63) * 2;
  const int wave = tx >> 6;             // 0..7
  const int ks = wave & 3;              // k-slice
  const int rh = wave >> 2;             // row half
  const int kb = ks * 128;
  const float* __restrict__ Wp = W + (size_t)kb * UN + u2;

  float acc[8][2] = {};
  for (int k = 0; k < 128; k += 4) {
    float4 a[8];
#pragma unroll
    for (int r = 0; r < 8; ++r)         // wave-uniform LDS broadcasts
      a[r] = *(const float4*)&At[(rh * 8 + r) * DD + kb + k];
#pragma unroll
    for (int j = 0; j < 4; ++j) {
      const float2 w = *(const float2*)(Wp + (size_t)(k + j) * UN);
#pragma unroll
      for (int r = 0; r < 8; ++r) {
        const float arj = ((const float*)&a[r])[j];
        acc[r][0] = fmaf(arj, w.x, acc[r][0]);
        acc[r][1] = fmaf(arj, w.y, acc[r][1]);
      }
    }
  }

#pragma unroll
  for (int r = 0; r < 8; ++r) {
    red[ks][rh * 8 + r][u2]     = acc[r][0];
    red[ks][rh * 8 + r][u2 + 1] = acc[r][1];
  }
  __syncthreads();

  // epilogue: 2048 outputs, 4/thread. thread = (u = tx>>2, rows (tx&3)*4..+3)
  const int u = tx >> 2;                // 0..127
  const int rq = (tx & 3) * 4;
  const float bu = bias[u];
  float o[4];
#pragma unroll
  for (int j = 0; j < 4; ++j) {
    const int row = rq + j;
    const float s = (red[0][row][u] + red[1][row][u]) +
                    (red[2][row][u] + red[3][row][u]);
    o[j] = K2 * (s + bu);
  }
  if (is_enc) {
    const int b = row_base >> 10;
    const int s0 = row_base & 1023;
    *(float4*)(wencT + (size_t)(b * UN + u) * SE + s0 + rq) =
        make_float4(o[0], o[1], o[2], o[3]);
  } else {
    const int rb0 = row_base - NB * SE;
#pragma unroll
    for (int j = 0; j < 4; ++j)
      wdec[(size_t)(rb0 + rq + j) * UN + u] = o[j];
  }
}

// ---------------------------------------------------------------------------
// K2: scores + softmax. One WG (1024 thr, 16 waves) per (b, t-pair): grid 256.
// exp-sharing: exp2(w+d_t) = exp2(w)*E_t with E_t = exp2(wdec_t) precomputed
// in LDS. Per (s,u): 1 exp + 2 rcp + 4 fma.
// score' = sum_u (-2 v_u) * rcp(fma(e, E_t, 1)); consts dropped (softmax
// shift-invariant, incl. v_b).
__global__ __launch_bounds__(1024, 1) void k_score(const float* __restrict__ wdec,
                                                   const float* __restrict__ v,
                                                   const float* __restrict__ wencT,
                                                   float* __restrict__ attn) {
  __shared__ __align__(16) float wdE[2][UN];        // exp2 of pre-scaled wdec
  __shared__ __align__(16) float nv2[UN];
  __shared__ __align__(16) float parts[4][2][SE];   // 32 KB
  __shared__ float redM[2][4], redS[2][4];

  const int wg = blockIdx.x;          // 0..255
  const int b = wg >> 6;
  const int t0 = (wg & 63) * 2;
  const int bt0 = b * TD + t0;
  const int tx = threadIdx.x;         // 0..1023

  if (tx < 2 * UN) {
    const int tt = tx >> 7, u = tx & 127;
    wdE[tt][u] = exp2_raw(wdec[(size_t)(bt0 + tt) * UN + u]);   // E_t[u]
    if (tx < UN) nv2[tx] = -2.0f * v[tx];
  }
  __syncthreads();

  const int sq = tx & 255;            // s-quad 0..255
  const int uq = tx >> 8;             // u quarter 0..3
  const float* wp = wencT + (size_t)(b * UN + uq * 32) * SE + sq * 4;

  float a0[4] = {}, a1[4] = {};
#pragma unroll 4
  for (int ui = 0; ui < 32; ++ui) {
    const int u = uq * 32 + ui;
    const float4 w = *(const float4*)(wp + (size_t)ui * SE);
    const float nvu = nv2[u];
    const float E0 = wdE[0][u];
    const float E1 = wdE[1][u];
#pragma unroll
    for (int j = 0; j < 4; ++j) {
      const float e = exp2_raw(((const float*)&w)[j]);   // shared by both t
      const float r0 = __builtin_amdgcn_rcpf(fmaf(e, E0, 1.0f));
      a0[j] = fmaf(nvu, r0, a0[j]);
      const float r1 = __builtin_amdgcn_rcpf(fmaf(e, E1, 1.0f));
      a1[j] = fmaf(nvu, r1, a1[j]);
    }
  }
  *(float4*)&parts[uq][0][sq * 4] = make_float4(a0[0], a0[1], a0[2], a0[3]);
  *(float4*)&parts[uq][1][sq * 4] = make_float4(a1[0], a1[1], a1[2], a1[3]);
  __syncthreads();

  // threads 0..511: tt = tx>>8, q = tx&255 -> 4 s-values each
  float sc[4], pv[4];
  const int tt = tx >> 8;             // valid for tx<512
  const int q = tx & 255;
  if (tx < 512) {
    const float4 g0 = *(const float4*)&parts[0][tt][q * 4];
    const float4 g1 = *(const float4*)&parts[1][tt][q * 4];
    const float4 g2 = *(const float4*)&parts[2][tt][q * 4];
    const float4 g3 = *(const float4*)&parts[3][tt][q * 4];
    sc[0] = (g0.x + g1.x) + (g2.x + g3.x);
    sc[1] = (g0.y + g1.y) + (g2.y + g3.y);
    sc[2] = (g0.z + g1.z) + (g2.z + g3.z);
    sc[3] = (g0.w + g1.w) + (g2.w + g3.w);
    float m = fmaxf(fmaxf(sc[0], sc[1]), fmaxf(sc[2], sc[3]));
#pragma unroll
    for (int off = 32; off; off >>= 1) m = fmaxf(m, __shfl_xor(m, off));
    if ((tx & 63) == 0) redM[tt][(tx >> 6) & 3] = m;
  }
  __syncthreads();
  if (tx < 512) {
    const float m = fmaxf(fmaxf(redM[tt][0], redM[tt][1]),
                          fmaxf(redM[tt][2], redM[tt][3]));
    float s = 0.f;
#pragma unroll
    for (int j = 0; j < 4; ++j) { pv[j] = __expf(sc[j] - m); s += pv[j]; }
#pragma unroll
    for (int off = 32; off; off >>= 1) s += __shfl_xor(s, off);
    if ((tx & 63) == 0) redS[tt][(tx >> 6) & 3] = s;
  }
  __syncthreads();
  if (tx < 512) {
    const float s = (redS[tt][0] + redS[tt][1]) + (redS[tt][2] + redS[tt][3]);
    const float rinv = 1.0f / s;
    float* arow = attn + (size_t)(bt0 + tt) * SE + q * 4;
    *(float4*)arow = make_float4(pv[0] * rinv, pv[1] * rinv, pv[2] * rinv, pv[3] * rinv);
  }
}

// ---------------------------------------------------------------------------
// K3: partial context over s-chunks of 128. grid = sc(8) x tg(16) x b(4) = 512.
// WG: 8 t-rows x all 512 d; thread = (d quad = (tx&127)*4, t-half = tx>>7 ->
// 4 rows). Per s: 1 float4 enc load + 4 wave-uniform LDS reads + 16 FMA.
__global__ __launch_bounds__(256, 2) void k_ctx_part(const float* __restrict__ attn,
                                                     const float* __restrict__ enc,
                                                     float* __restrict__ part) {
  __shared__ __align__(16) float at[8][128];
  const int wg = blockIdx.x;
  const int sch = wg & 7;
  const int tg = (wg >> 3) & 15;
  const int b = wg >> 7;
  const int tx = threadIdx.x;
  const int sbeg = sch * 128;
  {
    const int i = tx >> 5, c = (tx & 31) * 4;   // 8 rows x 32 float4
    *(float4*)&at[i][c] =
        *(const float4*)(attn + (size_t)(b * TD + tg * 8 + i) * SE + sbeg + c);
  }
  __syncthreads();
  const int d0 = (tx & 127) * 4;
  const int th = tx >> 7;               // 0/1: rows th*4 .. th*4+3 (wave-uniform)
  const float* ep = enc + ((size_t)b * SE + sbeg) * DD + d0;
  float4 acc[4] = {};
  for (int s = 0; s < 128; ++s) {
    const float4 ev = *(const float4*)(ep + (size_t)s * DD);
#pragma unroll
    for (int i = 0; i < 4; ++i) {
      const float aij = at[th * 4 + i][s];
      acc[i].x = fmaf(aij, ev.x, acc[i].x);
      acc[i].y = fmaf(aij, ev.y, acc[i].y);
      acc[i].z = fmaf(aij, ev.z, acc[i].z);
      acc[i].w = fmaf(aij, ev.w, acc[i].w);
    }
  }
  float* pb = part + ((size_t)sch * (NB * TD) + b * TD + tg * 8 + th * 4) * DD + d0;
#pragma unroll
  for (int i = 0; i < 4; ++i)
    *(float4*)(pb + (size_t)i * DD) = acc[i];
}

// ---------------------------------------------------------------------------
// K4: ctx = sum of 8 partials. grid 256 x 256 thr, float4/thread.
__global__ __launch_bounds__(256, 2) void k_red(const float* __restrict__ part,
                                                float* __restrict__ ctx) {
  const size_t N = (size_t)NB * TD * DD;
  const size_t i = ((size_t)blockIdx.x * 256 + threadIdx.x) * 4;
  float4 o = *(const float4*)(part + i);
#pragma unroll
  for (int s = 1; s < SSPLIT; ++s) {
    const float4 q = *(const float4*)(part + (size_t)s * N + i);
    o.x += q.x; o.y += q.y; o.z += q.z; o.w += q.w;
  }
  *(float4*)(ctx + i) = o;
}

extern "C" void kernel_launch(void* const* d_in, const int* in_sizes, int n_in,
                              void* d_out, int out_size, void* d_ws, size_t ws_size,
                              hipStream_t stream) {
  const float* dec = (const float*)d_in[0];
  const float* enc = (const float*)d_in[1];
  const float* W1  = (const float*)d_in[2];
  const float* b1  = (const float*)d_in[3];
  const float* W2  = (const float*)d_in[4];
  const float* b2  = (const float*)d_in[5];
  const float* v   = (const float*)d_in[6];
  // d_in[7] = v_b: skipped — softmax is invariant to a uniform score shift.

  float* ctx  = (float*)d_out;                        // [4,128,512]
  float* attn = (float*)d_out + (size_t)NB * TD * DD; // [4,128,1024]

  float* ws    = (float*)d_ws;
  float* wencT = ws;                                  // [4][128][1024] 2 MB
  float* wdec  = wencT + (size_t)NB * UN * SE;        // [512][128] 256 KB
  float* ctxpart = wdec + (size_t)NB * TD * UN;       // [8][512][512] 8 MB

  hipLaunchKernelGGL(k_proj, dim3(288), dim3(512), 0, stream,
                     enc, dec, W1, b1, W2, b2, wencT, wdec);
  hipLaunchKernelGGL(k_score, dim3(256), dim3(1024), 0, stream,
                     wdec, v, wencT, attn);
  hipLaunchKernelGGL(k_ctx_part, dim3(512), dim3(256), 0, stream, attn, enc, ctxpart);
  hipLaunchKernelGGL(k_red, dim3(256), dim3(256), 0, stream, ctxpart, ctx);
}

// Round 17
// 50.800 us; speedup vs baseline: 1.2266x; 1.0343x over previous
//
#include <hip/hip_runtime.h>
#include <math.h>

#define NB 4      // batch
#define TD 128    // T_DEC
#define SE 1024   // S_ENC
#define DD 512    // D
#define UN 128    // UNITS
#define KSPLIT 4

// raw v_exp_f32: D = 2^S0 (operands pre-scaled by 2*log2e at proj time)
__device__ __forceinline__ float exp2_raw(float x) {
  float r;
  asm("v_exp_f32 %0, %1" : "=v"(r) : "v"(x));
  return r;
}

// ---------------------------------------------------------------------------
// K1: projections, fused KSPLIT-in-WG.
// grid 288 x 512 thr (8 waves): blk 0..255 -> 16 enc rows, 256..287 -> 16 dec.
// Wave = (ks = wave&3 -> 128-k slice, rh = wave>>2 -> 8-row half).
// Thread: 8 rows x 2 u x 128 k = 16 FMA per coalesced float2 W load.
// k-partials reduced via LDS; bias + 2*log2e pre-scale fused; enc written
// TRANSPOSED to wencT[b][u][s], dec row-major to wdec.
__global__ __launch_bounds__(512, 2) void k_proj(const float* __restrict__ enc,
                                                 const float* __restrict__ dec,
                                                 const float* __restrict__ W1,
                                                 const float* __restrict__ b1,
                                                 const float* __restrict__ W2,
                                                 const float* __restrict__ b2,
                                                 float* __restrict__ wencT,
                                                 float* __restrict__ wdec) {
  __shared__ __align__(16) float At[16 * DD];          // 32 KB
  __shared__ float red[KSPLIT][16][129];               // 33 KB (pad vs banks)

  const int tx = threadIdx.x;           // 0..511
  const int rb = blockIdx.x;            // 0..287
  const bool is_enc = rb < 256;
  const int row_base = rb * 16;         // global row numbering
  const float* __restrict__ src = is_enc
      ? (enc + (size_t)row_base * DD)
      : (dec + (size_t)(row_base - NB * SE) * DD);
  const float* __restrict__ W = is_enc ? W1 : W2;
  const float* __restrict__ bias = is_enc ? b1 : b2;
  const float K2 = 2.88539008f;         // 2*log2(e)

  // stage 16 rows = 8192 contiguous floats (2048 float4, 4/thread)
#pragma unroll
  for (int i = 0; i < 4; ++i) {
    const int idx = (i * 512 + tx) * 4;
    *(float4*)&At[idx] = *(const float4*)(src + idx);
  }
  __syncthreads();

  const int u2 = (tx & 63) * 2;
  const int wave = tx >> 6;             // 0..7
  const int ks = wave & 3;              // k-slice
  const int rh = wave >> 2;             // row half
  const int kb = ks * 128;
  const float* __restrict__ Wp = W + (size_t)kb * UN + u2;

  float acc[8][2] = {};
  for (int k = 0; k < 128; k += 4) {
    float4 a[8];
#pragma unroll
    for (int r = 0; r < 8; ++r)         // wave-uniform LDS broadcasts
      a[r] = *(const float4*)&At[(rh * 8 + r) * DD + kb + k];
#pragma unroll
    for (int j = 0; j < 4; ++j) {
      const float2 w = *(const float2*)(Wp + (size_t)(k + j) * UN);
#pragma unroll
      for (int r = 0; r < 8; ++r) {
        const float arj = ((const float*)&a[r])[j];
        acc[r][0] = fmaf(arj, w.x, acc[r][0]);
        acc[r][1] = fmaf(arj, w.y, acc[r][1]);
      }
    }
  }

#pragma unroll
  for (int r = 0; r < 8; ++r) {
    red[ks][rh * 8 + r][u2]     = acc[r][0];
    red[ks][rh * 8 + r][u2 + 1] = acc[r][1];
  }
  __syncthreads();

  // epilogue: 2048 outputs, 4/thread. thread = (u = tx>>2, rows (tx&3)*4..+3)
  const int u = tx >> 2;                // 0..127
  const int rq = (tx & 3) * 4;
  const float bu = bias[u];
  float o[4];
#pragma unroll
  for (int j = 0; j < 4; ++j) {
    const int row = rq + j;
    const float s = (red[0][row][u] + red[1][row][u]) +
                    (red[2][row][u] + red[3][row][u]);
    o[j] = K2 * (s + bu);
  }
  if (is_enc) {
    const int b = row_base >> 10;
    const int s0 = row_base & 1023;
    *(float4*)(wencT + (size_t)(b * UN + u) * SE + s0 + rq) =
        make_float4(o[0], o[1], o[2], o[3]);
  } else {
    const int rb0 = row_base - NB * SE;
#pragma unroll
    for (int j = 0; j < 4; ++j)
      wdec[(size_t)(rb0 + rq + j) * UN + u] = o[j];
  }
}

// ---------------------------------------------------------------------------
// K2: scores + softmax. One WG (1024 thr, 16 waves) per (b, t-pair): grid 256.
// exp-sharing: exp2(w+d_t) = exp2(w)*E_t with E_t = exp2(wdec_t) precomputed
// in LDS. Per (s,u): 1 exp + 2 rcp + 4 fma.
// score' = sum_u (-2 v_u) * rcp(fma(e, E_t, 1)); consts dropped (softmax
// shift-invariant, incl. v_b).
__global__ __launch_bounds__(1024, 1) void k_score(const float* __restrict__ wdec,
                                                   const float* __restrict__ v,
                                                   const float* __restrict__ wencT,
                                                   float* __restrict__ attn) {
  __shared__ __align__(16) float wdE[2][UN];        // exp2 of pre-scaled wdec
  __shared__ __align__(16) float nv2[UN];
  __shared__ __align__(16) float parts[4][2][SE];   // 32 KB
  __shared__ float redM[2][4], redS[2][4];

  const int wg = blockIdx.x;          // 0..255
  const int b = wg >> 6;
  const int t0 = (wg & 63) * 2;
  const int bt0 = b * TD + t0;
  const int tx = threadIdx.x;         // 0..1023

  if (tx < 2 * UN) {
    const int tt = tx >> 7, u = tx & 127;
    wdE[tt][u] = exp2_raw(wdec[(size_t)(bt0 + tt) * UN + u]);   // E_t[u]
    if (tx < UN) nv2[tx] = -2.0f * v[tx];
  }
  __syncthreads();

  const int sq = tx & 255;            // s-quad 0..255
  const int uq = tx >> 8;             // u quarter 0..3
  const float* wp = wencT + (size_t)(b * UN + uq * 32) * SE + sq * 4;

  float a0[4] = {}, a1[4] = {};
#pragma unroll 4
  for (int ui = 0; ui < 32; ++ui) {
    const int u = uq * 32 + ui;
    const float4 w = *(const float4*)(wp + (size_t)ui * SE);
    const float nvu = nv2[u];
    const float E0 = wdE[0][u];
    const float E1 = wdE[1][u];
#pragma unroll
    for (int j = 0; j < 4; ++j) {
      const float e = exp2_raw(((const float*)&w)[j]);   // shared by both t
      const float r0 = __builtin_amdgcn_rcpf(fmaf(e, E0, 1.0f));
      a0[j] = fmaf(nvu, r0, a0[j]);
      const float r1 = __builtin_amdgcn_rcpf(fmaf(e, E1, 1.0f));
      a1[j] = fmaf(nvu, r1, a1[j]);
    }
  }
  *(float4*)&parts[uq][0][sq * 4] = make_float4(a0[0], a0[1], a0[2], a0[3]);
  *(float4*)&parts[uq][1][sq * 4] = make_float4(a1[0], a1[1], a1[2], a1[3]);
  __syncthreads();

  // threads 0..511: tt = tx>>8, q = tx&255 -> 4 s-values each
  float sc[4], pv[4];
  const int tt = tx >> 8;             // valid for tx<512
  const int q = tx & 255;
  if (tx < 512) {
    const float4 g0 = *(const float4*)&parts[0][tt][q * 4];
    const float4 g1 = *(const float4*)&parts[1][tt][q * 4];
    const float4 g2 = *(const float4*)&parts[2][tt][q * 4];
    const float4 g3 = *(const float4*)&parts[3][tt][q * 4];
    sc[0] = (g0.x + g1.x) + (g2.x + g3.x);
    sc[1] = (g0.y + g1.y) + (g2.y + g3.y);
    sc[2] = (g0.z + g1.z) + (g2.z + g3.z);
    sc[3] = (g0.w + g1.w) + (g2.w + g3.w);
    float m = fmaxf(fmaxf(sc[0], sc[1]), fmaxf(sc[2], sc[3]));
#pragma unroll
    for (int off = 32; off; off >>= 1) m = fmaxf(m, __shfl_xor(m, off));
    if ((tx & 63) == 0) redM[tt][(tx >> 6) & 3] = m;
  }
  __syncthreads();
  if (tx < 512) {
    const float m = fmaxf(fmaxf(redM[tt][0], redM[tt][1]),
                          fmaxf(redM[tt][2], redM[tt][3]));
    float s = 0.f;
#pragma unroll
    for (int j = 0; j < 4; ++j) { pv[j] = __expf(sc[j] - m); s += pv[j]; }
#pragma unroll
    for (int off = 32; off; off >>= 1) s += __shfl_xor(s, off);
    if ((tx & 63) == 0) redS[tt][(tx >> 6) & 3] = s;
  }
  __syncthreads();
  if (tx < 512) {
    const float s = (redS[tt][0] + redS[tt][1]) + (redS[tt][2] + redS[tt][3]);
    const float rinv = 1.0f / s;
    float* arow = attn + (size_t)(bt0 + tt) * SE + q * 4;
    *(float4*)arow = make_float4(pv[0] * rinv, pv[1] * rinv, pv[2] * rinv, pv[3] * rinv);
  }
}

// ---------------------------------------------------------------------------
// K3: context, fused s-split-in-WG (replaces k_ctx_part + k_red).
// grid 256 x 512 thr (8 waves): WG = (b, tg of 8 t-rows, dt of 128 d).
// Wave w covers s-chunk [128w, 128w+128); thread = 8t x 2d: 16 FMA per
// coalesced float2 enc load. attn tile (8x1024, 32 KB) staged once; 8
// wave-partials reduced via 32 KB LDS in fixed q-order (deterministic).
// 8 waves/CU (same residency as the split version); no global partials.
__global__ __launch_bounds__(512, 2) void k_ctx(const float* __restrict__ attn,
                                                const float* __restrict__ enc,
                                                float* __restrict__ ctx) {
  __shared__ __align__(16) float at[8][SE];        // 32 KB
  __shared__ __align__(16) float red[8][8][128];   // 32 KB

  const int wg = blockIdx.x;            // 0..255
  const int dt = wg & 3;                // d-tile of 128
  const int tg = (wg >> 2) & 15;        // 8 t-rows
  const int b = wg >> 6;
  const int tx = threadIdx.x;           // 0..511

  // stage attn rows: 8 x 1024 = 2048 float4, 4 per thread (coalesced)
#pragma unroll
  for (int i = 0; i < 4; ++i) {
    const int idx = i * 512 + tx;       // float4 index 0..2047
    const int row = idx >> 8;           // 256 float4 per row
    const int c = (idx & 255) * 4;
    *(float4*)&at[row][c] =
        *(const float4*)(attn + (size_t)(b * TD + tg * 8 + row) * SE + c);
  }
  __syncthreads();

  const int w = tx >> 6;                // wave 0..7 -> s-chunk
  const int dp = (tx & 63) * 2;         // d-pair within 128-d tile
  const int sbeg = w * 128;
  const float* ep = enc + ((size_t)b * SE + sbeg) * DD + dt * 128 + dp;

  float2 acc[8] = {};
  for (int s = 0; s < 128; ++s) {
    const float2 ev = *(const float2*)(ep + (size_t)s * DD);
#pragma unroll
    for (int t = 0; t < 8; ++t) {
      const float a = at[t][sbeg + s];  // wave-uniform broadcast
      acc[t].x = fmaf(a, ev.x, acc[t].x);
      acc[t].y = fmaf(a, ev.y, acc[t].y);
    }
  }
#pragma unroll
  for (int t = 0; t < 8; ++t)
    *(float2*)&red[w][t][dp] = acc[t];
  __syncthreads();

  // epilogue: 8t x 128d outputs, 512 thr -> one d-pair each; fixed q-order
  const int t = tx >> 6;                // 0..7
  const int d2 = (tx & 63) * 2;
  float ox = 0.f, oy = 0.f;
#pragma unroll
  for (int q = 0; q < 8; ++q) {
    ox += red[q][t][d2];
    oy += red[q][t][d2 + 1];
  }
  *(float2*)(ctx + (size_t)(b * TD + tg * 8 + t) * DD + dt * 128 + d2) =
      make_float2(ox, oy);
}

extern "C" void kernel_launch(void* const* d_in, const int* in_sizes, int n_in,
                              void* d_out, int out_size, void* d_ws, size_t ws_size,
                              hipStream_t stream) {
  const float* dec = (const float*)d_in[0];
  const float* enc = (const float*)d_in[1];
  const float* W1  = (const float*)d_in[2];
  const float* b1  = (const float*)d_in[3];
  const float* W2  = (const float*)d_in[4];
  const float* b2  = (const float*)d_in[5];
  const float* v   = (const float*)d_in[6];
  // d_in[7] = v_b: skipped — softmax is invariant to a uniform score shift.

  float* ctx  = (float*)d_out;                        // [4,128,512]
  float* attn = (float*)d_out + (size_t)NB * TD * DD; // [4,128,1024]

  float* ws    = (float*)d_ws;
  float* wencT = ws;                                  // [4][128][1024] 2 MB
  float* wdec  = wencT + (size_t)NB * UN * SE;        // [512][128] 256 KB

  hipLaunchKernelGGL(k_proj, dim3(288), dim3(512), 0, stream,
                     enc, dec, W1, b1, W2, b2, wencT, wdec);
  hipLaunchKernelGGL(k_score, dim3(256), dim3(1024), 0, stream,
                     wdec, v, wencT, attn);
  hipLaunchKernelGGL(k_ctx, dim3(256), dim3(512), 0, stream, attn, enc, ctx);
}